// Round 1
// baseline (244.496 us; speedup 1.0000x reference)
//
#include <hip/hip_runtime.h>
#include <stdint.h>
#include <stddef.h>

#define B_ 4
#define S_ 2048
#define D_ 1024
#define H_ 16
#define HD_ 64

typedef __bf16 bf16;
typedef __bf16 bf16x8 __attribute__((ext_vector_type(8)));
typedef __bf16 bf16x4 __attribute__((ext_vector_type(4)));
typedef float f32x4 __attribute__((ext_vector_type(4)));

__device__ __forceinline__ f32x4 mfma16(bf16x8 a, bf16x8 b, f32x4 c) {
  return __builtin_amdgcn_mfma_f32_16x16x32_bf16(a, b, c, 0, 0, 0);
}

// global -> LDS direct copy, 16B per lane. dst must be wave-uniform; HW writes
// dst + lane*16. Global src address is per-lane (enables source pre-swizzle).
__device__ __forceinline__ void gload_lds16(const void* g, void* l) {
  __builtin_amdgcn_global_load_lds(
      (__attribute__((address_space(1))) uint32_t*)(uintptr_t)g,
      (__attribute__((address_space(3))) uint32_t*)l, 16, 0, 0);
}

// ---------------------------------------------------------------------------
// f32 -> bf16 weight conversion (4 x [1024x1024])
// ---------------------------------------------------------------------------
__global__ __launch_bounds__(256) void convert_w(
    const float* __restrict__ a, const float* __restrict__ b,
    const float* __restrict__ c, const float* __restrict__ d,
    bf16* __restrict__ out) {
  int i = (blockIdx.x * 256 + threadIdx.x) * 4;
  const float* srcs[4] = {a, b, c, d};
#pragma unroll
  for (int w = 0; w < 4; ++w) {
    f32x4 x = *(const f32x4*)(srcs[w] + i);
    bf16x4 v;
    v[0] = (bf16)x[0]; v[1] = (bf16)x[1]; v[2] = (bf16)x[2]; v[3] = (bf16)x[3];
    *(bf16x4*)(out + (size_t)w * (D_ * D_) + i) = v;
  }
}

// ---------------------------------------------------------------------------
// GEMM: C[8192][1024] = A[8192][1024] @ W[1024][1024]^T + bias
// 128x128 tile, BK=64, 4 waves (2x2), each wave 64x64 via 4x4 16x16x32 frags.
// LDS tiles [128][64] bf16, 16B-block XOR(row&7) swizzle (both-sides, rule 21).
// OUT_MODE: 0 = bf16 head layout [B][H][S][HD]
//           1 = bf16 transposed head layout [B][H][HD][S]  (for V)
//           2 = f32 row-major [8192][1024] (final output)
// ---------------------------------------------------------------------------
template <int A_BF16, int OUT_MODE>
__global__ __launch_bounds__(256, 2) void gemm_proj(
    const void* __restrict__ Aptr, const bf16* __restrict__ Wb,
    const float* __restrict__ bias, void* __restrict__ Out) {
  __shared__ alignas(128) char lds[32768];  // A: [0,16K)  B: [16K,32K)
  const int tid = threadIdx.x;
  const int lane = tid & 63;
  const int wave = tid >> 6;
  const int m0 = blockIdx.x * 128;
  const int n0 = blockIdx.y * 128;
  const int wr = wave >> 1, wc = wave & 1;

  f32x4 acc[4][4] = {};

  for (int kt = 0; kt < 16; ++kt) {
    const int k0 = kt * 64;
    // ---- stage A tile [128 rows m][64 k]
    if (A_BF16) {
      const bf16* A = (const bf16*)Aptr;
#pragma unroll
      for (int j = 0; j < 4; ++j) {
        int slot = j * 256 + tid;
        int row = slot >> 3, kb = slot & 7;
        gload_lds16(A + (size_t)(m0 + row) * D_ + k0 + ((kb ^ (row & 7)) << 3),
                    lds + j * 4096 + wave * 1024);
      }
    } else {
      const float* A = (const float*)Aptr;
#pragma unroll
      for (int j = 0; j < 4; ++j) {
        int slot = j * 256 + tid;
        int row = slot >> 3, kb = slot & 7;
        const float* src = A + (size_t)(m0 + row) * D_ + k0 + (kb << 3);
        f32x4 x0 = *(const f32x4*)src;
        f32x4 x1 = *(const f32x4*)(src + 4);
        bf16x8 v;
        v[0] = (bf16)x0[0]; v[1] = (bf16)x0[1]; v[2] = (bf16)x0[2]; v[3] = (bf16)x0[3];
        v[4] = (bf16)x1[0]; v[5] = (bf16)x1[1]; v[6] = (bf16)x1[2]; v[7] = (bf16)x1[3];
        *(bf16x8*)(lds + row * 128 + ((kb ^ (row & 7)) << 4)) = v;
      }
    }
    // ---- stage B tile [128 rows n][64 k] (weights already bf16)
#pragma unroll
    for (int j = 0; j < 4; ++j) {
      int slot = j * 256 + tid;
      int row = slot >> 3, kb = slot & 7;
      gload_lds16(Wb + (size_t)(n0 + row) * D_ + k0 + ((kb ^ (row & 7)) << 3),
                  lds + 16384 + j * 4096 + wave * 1024);
    }
    __syncthreads();
    // ---- compute
#pragma unroll
    for (int ks = 0; ks < 2; ++ks) {
      bf16x8 af[4], bfr[4];
#pragma unroll
      for (int f = 0; f < 4; ++f) {
        int ar = wr * 64 + f * 16 + (lane & 15);
        af[f] = *(const bf16x8*)(lds + ar * 128 +
                                 (((ks * 4 + (lane >> 4)) ^ (ar & 7)) << 4));
        int br = wc * 64 + f * 16 + (lane & 15);
        bfr[f] = *(const bf16x8*)(lds + 16384 + br * 128 +
                                  (((ks * 4 + (lane >> 4)) ^ (br & 7)) << 4));
      }
#pragma unroll
      for (int i = 0; i < 4; ++i)
#pragma unroll
        for (int j = 0; j < 4; ++j)
          acc[i][j] = mfma16(af[i], bfr[j], acc[i][j]);
    }
    __syncthreads();
  }

  // ---- epilogue.  C frag mapping: col = lane&15, row = (lane>>4)*4 + r.
#pragma unroll
  for (int j = 0; j < 4; ++j) {
    const int col = n0 + wc * 64 + j * 16 + (lane & 15);
    const float bv = bias[col];
#pragma unroll
    for (int i = 0; i < 4; ++i) {
      const int row0 = m0 + wr * 64 + i * 16 + ((lane >> 4) << 2);
      if (OUT_MODE == 2) {
        float* O = (float*)Out;
#pragma unroll
        for (int r = 0; r < 4; ++r)
          O[(size_t)(row0 + r) * D_ + col] = acc[i][j][r] + bv;
      } else if (OUT_MODE == 0) {
        bf16* O = (bf16*)Out;
        const int h = col >> 6, hd = col & 63;
#pragma unroll
        for (int r = 0; r < 4; ++r) {
          int row = row0 + r;
          int b = row >> 11, s = row & (S_ - 1);
          O[(((size_t)(b * H_ + h) * S_ + s) << 6) + hd] =
              (bf16)(acc[i][j][r] + bv);
        }
      } else {  // OUT_MODE == 1: V transposed; 4 acc rows are s-contiguous
        bf16* O = (bf16*)Out;
        const int h = col >> 6, hd = col & 63;
        int b = row0 >> 11, s0 = row0 & (S_ - 1);
        bf16x4 pk;
#pragma unroll
        for (int r = 0; r < 4; ++r) pk[r] = (bf16)(acc[i][j][r] + bv);
        *(bf16x4*)(O + ((size_t)(b * H_ + h) * HD_ + hd) * S_ + s0) = pk;
      }
    }
  }
}

// ---------------------------------------------------------------------------
// Attention: per block = one (b,h) and 128 q-rows (wave -> 32 q-rows).
// No-max softmax (logits bounded; exp safe in f32): den = sum exp, O = sum exp*V.
// K tile [128][64], V^T tile [64][128] staged via gload_lds + XOR swizzle.
// P round-trips through per-wave LDS [32][128] bf16 (swizzled).
// ---------------------------------------------------------------------------
__global__ __launch_bounds__(256, 2) void attn_kernel(
    const bf16* __restrict__ Qh, const bf16* __restrict__ Kh,
    const bf16* __restrict__ Vt, bf16* __restrict__ AO) {
  __shared__ alignas(128) char lds[65536];  // K:[0,16K) V:[16K,32K) P:[32K,64K)
  const int tid = threadIdx.x, lane = tid & 63, wave = tid >> 6;
  const int bh = blockIdx.y;
  const int q0 = blockIdx.x * 128 + wave * 32;
  const bf16* Qb = Qh + (size_t)bh * S_ * HD_;
  const bf16* Kb = Kh + (size_t)bh * S_ * HD_;
  const bf16* Vb = Vt + (size_t)bh * HD_ * S_;
  char* Plds = lds + 32768 + wave * 8192;

  // Q fragments for this wave's 32 rows, kept in registers all kernel.
  bf16x8 qf[2][2];
#pragma unroll
  for (int i = 0; i < 2; ++i)
#pragma unroll
    for (int ks = 0; ks < 2; ++ks)
      qf[i][ks] = *(const bf16x8*)(Qb +
                                   (size_t)(q0 + i * 16 + (lane & 15)) * HD_ +
                                   ks * 32 + ((lane >> 4) << 3));

  f32x4 oacc[2][4] = {};
  float den[2][4] = {};

  for (int kt = 0; kt < 16; ++kt) {
    const int kv0 = kt * 128;
    // stage K [128 kv][64 hd]
#pragma unroll
    for (int j = 0; j < 4; ++j) {
      int slot = j * 256 + tid, row = slot >> 3, kb = slot & 7;
      gload_lds16(Kb + (size_t)(kv0 + row) * HD_ + ((kb ^ (row & 7)) << 3),
                  lds + j * 4096 + wave * 1024);
    }
    // stage V^T [64 hd][128 kv]
#pragma unroll
    for (int j = 0; j < 4; ++j) {
      int slot = j * 256 + tid, row = slot >> 4, kb = slot & 15;
      gload_lds16(Vb + (size_t)row * S_ + kv0 + ((kb ^ (row & 7)) << 3),
                  lds + 16384 + j * 4096 + wave * 1024);
    }
    __syncthreads();

    // S = Q @ K^T  -> frags: col = kv (lane&15), row = q ((lane>>4)*4+r)
    f32x4 sacc[2][8] = {};
#pragma unroll
    for (int nf = 0; nf < 8; ++nf) {
#pragma unroll
      for (int ks = 0; ks < 2; ++ks) {
        int kr = nf * 16 + (lane & 15);
        bf16x8 kf = *(const bf16x8*)(lds + kr * 128 +
                                     (((ks * 4 + (lane >> 4)) ^ (kr & 7)) << 4));
        sacc[0][nf] = mfma16(qf[0][ks], kf, sacc[0][nf]);
        sacc[1][nf] = mfma16(qf[1][ks], kf, sacc[1][nf]);
      }
    }

    // P = exp(S/8); row-sums -> den; P -> per-wave LDS (bf16, swizzled)
#pragma unroll
    for (int i = 0; i < 2; ++i) {
      float rs[4] = {0.f, 0.f, 0.f, 0.f};
#pragma unroll
      for (int nf = 0; nf < 8; ++nf) {
        int pcb = nf * 2 + ((lane & 15) >> 3);  // 16B-block index of col
#pragma unroll
        for (int r = 0; r < 4; ++r) {
          float p = __expf(sacc[i][nf][r] * 0.125f);
          rs[r] += p;
          int pr = i * 16 + ((lane >> 4) << 2) + r;
          *(bf16*)(Plds + pr * 256 + ((pcb ^ (pr & 7)) << 4) +
                   ((lane & 7) << 1)) = (bf16)p;
        }
      }
#pragma unroll
      for (int r = 0; r < 4; ++r) {
        float v = rs[r];
        v += __shfl_xor(v, 1, 16);
        v += __shfl_xor(v, 2, 16);
        v += __shfl_xor(v, 4, 16);
        v += __shfl_xor(v, 8, 16);
        den[i][r] += v;
      }
    }

    // O += P @ V   (A = P from LDS, B = V^T rows = hd)
#pragma unroll
    for (int ks = 0; ks < 4; ++ks) {
      bf16x8 pa[2];
#pragma unroll
      for (int i = 0; i < 2; ++i) {
        int pr = i * 16 + (lane & 15);
        pa[i] = *(const bf16x8*)(Plds + pr * 256 +
                                 (((ks * 4 + (lane >> 4)) ^ (pr & 7)) << 4));
      }
#pragma unroll
      for (int nf = 0; nf < 4; ++nf) {
        int vr = nf * 16 + (lane & 15);
        bf16x8 vf = *(const bf16x8*)(lds + 16384 + vr * 256 +
                                     (((ks * 4 + (lane >> 4)) ^ (vr & 7)) << 4));
        oacc[0][nf] = mfma16(pa[0], vf, oacc[0][nf]);
        oacc[1][nf] = mfma16(pa[1], vf, oacc[1][nf]);
      }
    }
    __syncthreads();
  }

  // epilogue: divide by den, write [B][S][H*HD] bf16
  const int b = bh >> 4, h = bh & 15;
#pragma unroll
  for (int i = 0; i < 2; ++i)
#pragma unroll
    for (int nf = 0; nf < 4; ++nf)
#pragma unroll
      for (int r = 0; r < 4; ++r) {
        int s = q0 + i * 16 + ((lane >> 4) << 2) + r;
        int hd = nf * 16 + (lane & 15);
        float val = oacc[i][nf][r] / den[i][r];
        AO[((size_t)(b * S_ + s) << 10) + h * 64 + hd] = (bf16)val;
      }
}

// ---------------------------------------------------------------------------
extern "C" void kernel_launch(void* const* d_in, const int* in_sizes, int n_in,
                              void* d_out, int out_size, void* d_ws,
                              size_t ws_size, hipStream_t stream) {
  (void)in_sizes; (void)n_in; (void)out_size; (void)ws_size;
  const float* q  = (const float*)d_in[0];
  const float* k  = (const float*)d_in[1];
  const float* v  = (const float*)d_in[2];
  const float* Wq = (const float*)d_in[3];
  const float* bq = (const float*)d_in[4];
  const float* Wk = (const float*)d_in[5];
  const float* bk = (const float*)d_in[6];
  const float* Wv = (const float*)d_in[7];
  const float* bv = (const float*)d_in[8];
  const float* Wo = (const float*)d_in[9];
  const float* bo = (const float*)d_in[10];

  bf16* ws = (bf16*)d_ws;
  const size_t WSZ = (size_t)D_ * D_;             // 1M elems per weight
  const size_t TSZ = (size_t)B_ * H_ * S_ * HD_;  // 8.39M elems per tensor
  bf16* Wqb = ws;
  bf16* Wkb = ws + WSZ;
  bf16* Wvb = ws + 2 * WSZ;
  bf16* Wob = ws + 3 * WSZ;
  bf16* Qh = ws + 4 * WSZ;
  bf16* Kh = Qh + TSZ;
  bf16* Vt = Kh + TSZ;
  bf16* AO = Vt + TSZ;

  convert_w<<<dim3(1024), dim3(256), 0, stream>>>(Wq, Wk, Wv, Wo, ws);
  dim3 gg(64, 8), bb(256);
  gemm_proj<0, 0><<<gg, bb, 0, stream>>>(q, Wqb, bq, Qh);
  gemm_proj<0, 0><<<gg, bb, 0, stream>>>(k, Wkb, bk, Kh);
  gemm_proj<0, 1><<<gg, bb, 0, stream>>>(v, Wvb, bv, Vt);
  attn_kernel<<<dim3(16, 64), dim3(256), 0, stream>>>(Qh, Kh, Vt, AO);
  gemm_proj<1, 2><<<gg, bb, 0, stream>>>(AO, Wob, bo, d_out);
}

// Round 2
// 205.799 us; speedup vs baseline: 1.1880x; 1.1880x over previous
//
#include <hip/hip_runtime.h>
#include <stdint.h>
#include <stddef.h>

#define B_ 4
#define S_ 2048
#define D_ 1024
#define H_ 16
#define HD_ 64

typedef __bf16 bf16;
typedef __bf16 bf16x8 __attribute__((ext_vector_type(8)));
typedef __bf16 bf16x4 __attribute__((ext_vector_type(4)));
typedef float f32x4 __attribute__((ext_vector_type(4)));
typedef float f32x16 __attribute__((ext_vector_type(16)));
typedef uint32_t u32x4 __attribute__((ext_vector_type(4)));

__device__ __forceinline__ f32x4 mfma16(bf16x8 a, bf16x8 b, f32x4 c) {
  return __builtin_amdgcn_mfma_f32_16x16x32_bf16(a, b, c, 0, 0, 0);
}
__device__ __forceinline__ f32x16 mfma32(bf16x8 a, bf16x8 b, f32x16 c) {
  return __builtin_amdgcn_mfma_f32_32x32x16_bf16(a, b, c, 0, 0, 0);
}

// global -> LDS direct copy, 16B per lane. LDS dst is wave-uniform base
// (HW writes base + lane*16); global src is per-lane.
__device__ __forceinline__ void gload_lds16(const void* g, void* l) {
  __builtin_amdgcn_global_load_lds(
      (__attribute__((address_space(1))) uint32_t*)(uintptr_t)g,
      (__attribute__((address_space(3))) uint32_t*)l, 16, 0, 0);
}

__device__ __forceinline__ uint32_t cvt_pk(float lo, float hi) {
  uint32_t r;
  asm volatile("v_cvt_pk_bf16_f32 %0, %1, %2" : "=v"(r) : "v"(lo), "v"(hi));
  return r;
}

// v_permlane32_swap_b32 semantics:
//   a' = lane<32 ? a : b[lane-32];  b' = lane<32 ? a[lane+32] : b
__device__ __forceinline__ void pl_swap(uint32_t& a, uint32_t& b) {
#if __has_builtin(__builtin_amdgcn_permlane32_swap)
  typedef int i32x2_t __attribute__((ext_vector_type(2)));
  i32x2_t r = __builtin_amdgcn_permlane32_swap((int)a, (int)b, false, false);
  a = (uint32_t)r[0];
  b = (uint32_t)r[1];
#else
  uint32_t pa_ = (uint32_t)__shfl_xor((int)a, 32);
  uint32_t pb_ = (uint32_t)__shfl_xor((int)b, 32);
  bool hi_ = (threadIdx.x & 32) != 0;
  uint32_t na = hi_ ? pb_ : a;
  uint32_t nb = hi_ ? b : pa_;
  a = na;
  b = nb;
#endif
}

__device__ __forceinline__ bf16x8 pack4(uint32_t a, uint32_t b, uint32_t c,
                                        uint32_t d) {
  u32x4 v = {a, b, c, d};
  return __builtin_bit_cast(bf16x8, v);
}

// ---------------------------------------------------------------------------
// f32 -> bf16 weight conversion (4 x [1024x1024])
// ---------------------------------------------------------------------------
__global__ __launch_bounds__(256) void convert_w(
    const float* __restrict__ a, const float* __restrict__ b,
    const float* __restrict__ c, const float* __restrict__ d,
    bf16* __restrict__ out) {
  int i = (blockIdx.x * 256 + threadIdx.x) * 4;
  const float* srcs[4] = {a, b, c, d};
#pragma unroll
  for (int w = 0; w < 4; ++w) {
    f32x4 x = *(const f32x4*)(srcs[w] + i);
    bf16x4 v;
    v[0] = (bf16)x[0]; v[1] = (bf16)x[1]; v[2] = (bf16)x[2]; v[3] = (bf16)x[3];
    *(bf16x4*)(out + (size_t)w * (D_ * D_) + i) = v;
  }
}

// ---------------------------------------------------------------------------
// GEMM: C[8192][1024] = A[8192][1024] @ W[1024][1024]^T + bias  (unchanged)
// ---------------------------------------------------------------------------
template <int A_BF16, int OUT_MODE>
__global__ __launch_bounds__(256, 2) void gemm_proj(
    const void* __restrict__ Aptr, const bf16* __restrict__ Wb,
    const float* __restrict__ bias, void* __restrict__ Out) {
  __shared__ alignas(128) char lds[32768];  // A: [0,16K)  B: [16K,32K)
  const int tid = threadIdx.x;
  const int lane = tid & 63;
  const int wave = tid >> 6;
  const int m0 = blockIdx.x * 128;
  const int n0 = blockIdx.y * 128;
  const int wr = wave >> 1, wc = wave & 1;

  f32x4 acc[4][4] = {};

  for (int kt = 0; kt < 16; ++kt) {
    const int k0 = kt * 64;
    if (A_BF16) {
      const bf16* A = (const bf16*)Aptr;
#pragma unroll
      for (int j = 0; j < 4; ++j) {
        int slot = j * 256 + tid;
        int row = slot >> 3, kb = slot & 7;
        gload_lds16(A + (size_t)(m0 + row) * D_ + k0 + ((kb ^ (row & 7)) << 3),
                    lds + j * 4096 + wave * 1024);
      }
    } else {
      const float* A = (const float*)Aptr;
#pragma unroll
      for (int j = 0; j < 4; ++j) {
        int slot = j * 256 + tid;
        int row = slot >> 3, kb = slot & 7;
        const float* src = A + (size_t)(m0 + row) * D_ + k0 + (kb << 3);
        f32x4 x0 = *(const f32x4*)src;
        f32x4 x1 = *(const f32x4*)(src + 4);
        bf16x8 v;
        v[0] = (bf16)x0[0]; v[1] = (bf16)x0[1]; v[2] = (bf16)x0[2]; v[3] = (bf16)x0[3];
        v[4] = (bf16)x1[0]; v[5] = (bf16)x1[1]; v[6] = (bf16)x1[2]; v[7] = (bf16)x1[3];
        *(bf16x8*)(lds + row * 128 + ((kb ^ (row & 7)) << 4)) = v;
      }
    }
#pragma unroll
    for (int j = 0; j < 4; ++j) {
      int slot = j * 256 + tid;
      int row = slot >> 3, kb = slot & 7;
      gload_lds16(Wb + (size_t)(n0 + row) * D_ + k0 + ((kb ^ (row & 7)) << 3),
                  lds + 16384 + j * 4096 + wave * 1024);
    }
    __syncthreads();
#pragma unroll
    for (int ks = 0; ks < 2; ++ks) {
      bf16x8 af[4], bfr[4];
#pragma unroll
      for (int f = 0; f < 4; ++f) {
        int ar = wr * 64 + f * 16 + (lane & 15);
        af[f] = *(const bf16x8*)(lds + ar * 128 +
                                 (((ks * 4 + (lane >> 4)) ^ (ar & 7)) << 4));
        int br = wc * 64 + f * 16 + (lane & 15);
        bfr[f] = *(const bf16x8*)(lds + 16384 + br * 128 +
                                  (((ks * 4 + (lane >> 4)) ^ (br & 7)) << 4));
      }
#pragma unroll
      for (int i = 0; i < 4; ++i)
#pragma unroll
        for (int j = 0; j < 4; ++j)
          acc[i][j] = mfma16(af[i], bfr[j], acc[i][j]);
    }
    __syncthreads();
  }

#pragma unroll
  for (int j = 0; j < 4; ++j) {
    const int col = n0 + wc * 64 + j * 16 + (lane & 15);
    const float bv = bias[col];
#pragma unroll
    for (int i = 0; i < 4; ++i) {
      const int row0 = m0 + wr * 64 + i * 16 + ((lane >> 4) << 2);
      if (OUT_MODE == 2) {
        float* O = (float*)Out;
#pragma unroll
        for (int r = 0; r < 4; ++r)
          O[(size_t)(row0 + r) * D_ + col] = acc[i][j][r] + bv;
      } else if (OUT_MODE == 0) {
        bf16* O = (bf16*)Out;
        const int h = col >> 6, hd = col & 63;
#pragma unroll
        for (int r = 0; r < 4; ++r) {
          int row = row0 + r;
          int b = row >> 11, s = row & (S_ - 1);
          O[(((size_t)(b * H_ + h) * S_ + s) << 6) + hd] =
              (bf16)(acc[i][j][r] + bv);
        }
      } else {  // V transposed [B][H][HD][S]
        bf16* O = (bf16*)Out;
        const int h = col >> 6, hd = col & 63;
        int b = row0 >> 11, s0 = row0 & (S_ - 1);
        bf16x4 pk;
#pragma unroll
        for (int r = 0; r < 4; ++r) pk[r] = (bf16)(acc[i][j][r] + bv);
        *(bf16x4*)(O + ((size_t)(b * H_ + h) * HD_ + hd) * S_ + s0) = pk;
      }
    }
  }
}

// ---------------------------------------------------------------------------
// Attention v2: 32x32x16 MFMA, swapped QK^T, in-register softmax (T12),
// fragment-major K/V LDS (zero bank conflicts), double-buffered prefetch.
// Block = 4 waves x 32 q-rows = 128 q. KVBLK = 64 (2 kv-blocks of 32).
//
// Swapped QK^T: S^T[kv][q] = mfma(A=K, B=Q). Lane holds q = lane&31,
// kv = crow(r,hi) = (r&3) + 8*(r>>2) + 4*hi  (hi = lane>>5).
// cvt_pk pairs (p[2m],p[2m+1]) are kv-adjacent; permlane32_swap on
// (w0,w2),(w1,w3),(w4,w6),(w5,w7) yields the two PV A-frags per kv-block.
// ---------------------------------------------------------------------------
__global__ __launch_bounds__(256, 2) void attn_kernel(
    const bf16* __restrict__ Qh, const bf16* __restrict__ Kh,
    const bf16* __restrict__ Vt, bf16* __restrict__ AO) {
  // frag-major: K frags 0..7 (kb*4+ks) at [0,8K); V frags 8..15 (ks16*2+ht)
  // at [8K,16K); double buffer.
  __shared__ alignas(128) char lds[2][16384];
  const int tid = threadIdx.x, lane = tid & 63, wave = tid >> 6;
  const int hi = lane >> 5, l31 = lane & 31;
  const int bh = blockIdx.y;
  const int q0 = blockIdx.x * 128 + wave * 32;
  const bf16* Qb = Qh + (size_t)bh * S_ * HD_;
  const bf16* Kb = Kh + (size_t)bh * S_ * HD_;
  const bf16* Vb = Vt + (size_t)bh * HD_ * S_;

  // Q B-frags (col q = lane&31, k = hd = ks*16 + hi*8 + j), in regs all kernel
  bf16x8 qf[4];
#pragma unroll
  for (int ks = 0; ks < 4; ++ks)
    qf[ks] = *(const bf16x8*)(Qb + (size_t)(q0 + l31) * HD_ + ks * 16 + hi * 8);

  // staging assignment: wave w stages frags {w, 4+w, 8+w, 12+w}
  const bf16* gs[4];
  int lo_[4], ginc[4];
#pragma unroll
  for (int j = 0; j < 4; ++j) {
    int f = j * 4 + wave;
    lo_[j] = f * 1024;
    if (f < 8) {  // K frag: kb = f>>2, ks = f&3
      gs[j] = Kb + (size_t)((f >> 2) * 32 + l31) * HD_ + (f & 3) * 16 + hi * 8;
      ginc[j] = 64 * HD_;
    } else {  // V frag: g = f-8: ht = g&1, ks16 = g>>1
      int g = f - 8;
      gs[j] = Vb + (size_t)((g & 1) * 32 + l31) * S_ + (g >> 1) * 16 + hi * 8;
      ginc[j] = 64;
    }
  }

  f32x16 oacc[2] = {};
  float den = 0.f;

  // prologue: stage tile 0 into buf 0
#pragma unroll
  for (int j = 0; j < 4; ++j) {
    gload_lds16(gs[j], &lds[0][lo_[j]]);
    gs[j] += ginc[j];
  }
  __syncthreads();

  for (int t = 0; t < 32; ++t) {
    const int cur = t & 1;
    if (t < 31) {  // prefetch next tile; latency hides under compute
#pragma unroll
      for (int j = 0; j < 4; ++j) {
        gload_lds16(gs[j], &lds[cur ^ 1][lo_[j]]);
        gs[j] += ginc[j];
      }
    }
    const char* kbuf = lds[cur];
    const char* vbuf = lds[cur] + 8192;
#pragma unroll
    for (int kb = 0; kb < 2; ++kb) {
      f32x16 s = {};
#pragma unroll
      for (int ks = 0; ks < 4; ++ks) {
        bf16x8 kf = *(const bf16x8*)(kbuf + (kb * 4 + ks) * 1024 + lane * 16);
        s = mfma32(kf, qf[ks], s);
      }
      float p[16];
      float dl = 0.f;
#pragma unroll
      for (int r = 0; r < 16; ++r) {
        p[r] = __expf(s[r] * 0.125f);
        dl += p[r];
      }
      den += dl;
      uint32_t w0 = cvt_pk(p[0], p[1]), w1 = cvt_pk(p[2], p[3]),
               w2 = cvt_pk(p[4], p[5]), w3 = cvt_pk(p[6], p[7]),
               w4 = cvt_pk(p[8], p[9]), w5 = cvt_pk(p[10], p[11]),
               w6 = cvt_pk(p[12], p[13]), w7 = cvt_pk(p[14], p[15]);
      pl_swap(w0, w2);
      pl_swap(w1, w3);
      pl_swap(w4, w6);
      pl_swap(w5, w7);
      bf16x8 pa0 = pack4(w0, w1, w2, w3);  // kslot 2*kb+0
      bf16x8 pa1 = pack4(w4, w5, w6, w7);  // kslot 2*kb+1
#pragma unroll
      for (int ht = 0; ht < 2; ++ht) {
        bf16x8 vf0 =
            *(const bf16x8*)(vbuf + ((kb * 2 + 0) * 2 + ht) * 1024 + lane * 16);
        oacc[ht] = mfma32(pa0, vf0, oacc[ht]);
        bf16x8 vf1 =
            *(const bf16x8*)(vbuf + ((kb * 2 + 1) * 2 + ht) * 1024 + lane * 16);
        oacc[ht] = mfma32(pa1, vf1, oacc[ht]);
      }
    }
    __syncthreads();  // vmcnt(0)+lgkmcnt(0)+barrier: next tile staged, cur free
  }

  // epilogue: combine hi-halves of den, divide, store
  float rden = 1.0f / (den + __shfl_xor(den, 32));
  const int b = bh >> 4, h = bh & 15;
#pragma unroll
  for (int r = 0; r < 16; ++r) {
    int qr = (r & 3) + 8 * (r >> 2) + 4 * hi;
    float dr = __shfl(rden, qr);  // lane qr holds rden for q-row qr
    size_t base = ((size_t)(b * S_ + q0 + qr)) * D_ + h * 64;
#pragma unroll
    for (int ht = 0; ht < 2; ++ht)
      AO[base + ht * 32 + l31] = (bf16)(oacc[ht][r] * dr);
  }
}

// ---------------------------------------------------------------------------
extern "C" void kernel_launch(void* const* d_in, const int* in_sizes, int n_in,
                              void* d_out, int out_size, void* d_ws,
                              size_t ws_size, hipStream_t stream) {
  (void)in_sizes; (void)n_in; (void)out_size; (void)ws_size;
  const float* q  = (const float*)d_in[0];
  const float* k  = (const float*)d_in[1];
  const float* v  = (const float*)d_in[2];
  const float* Wq = (const float*)d_in[3];
  const float* bq = (const float*)d_in[4];
  const float* Wk = (const float*)d_in[5];
  const float* bk = (const float*)d_in[6];
  const float* Wv = (const float*)d_in[7];
  const float* bv = (const float*)d_in[8];
  const float* Wo = (const float*)d_in[9];
  const float* bo = (const float*)d_in[10];

  bf16* ws = (bf16*)d_ws;
  const size_t WSZ = (size_t)D_ * D_;
  const size_t TSZ = (size_t)B_ * H_ * S_ * HD_;
  bf16* Wqb = ws;
  bf16* Wkb = ws + WSZ;
  bf16* Wvb = ws + 2 * WSZ;
  bf16* Wob = ws + 3 * WSZ;
  bf16* Qh = ws + 4 * WSZ;
  bf16* Kh = Qh + TSZ;
  bf16* Vt = Kh + TSZ;
  bf16* AO = Vt + TSZ;

  convert_w<<<dim3(1024), dim3(256), 0, stream>>>(Wq, Wk, Wv, Wo, ws);
  dim3 gg(64, 8), bb(256);
  gemm_proj<0, 0><<<gg, bb, 0, stream>>>(q, Wqb, bq, Qh);
  gemm_proj<0, 0><<<gg, bb, 0, stream>>>(k, Wkb, bk, Kh);
  gemm_proj<0, 1><<<gg, bb, 0, stream>>>(v, Wvb, bv, Vt);
  attn_kernel<<<dim3(16, 64), dim3(256), 0, stream>>>(Qh, Kh, Vt, AO);
  gemm_proj<1, 2><<<gg, bb, 0, stream>>>(AO, Wob, bo, d_out);
}

// Round 3
// 184.522 us; speedup vs baseline: 1.3250x; 1.1153x over previous
//
#include <hip/hip_runtime.h>
#include <stdint.h>
#include <stddef.h>

#define B_ 4
#define S_ 2048
#define D_ 1024
#define H_ 16
#define HD_ 64

// exp(x/8) = 2^(x*0.125*log2(e)); fold this into the Q projection output.
#define QSCALE 0.18033688f

typedef __bf16 bf16;
typedef __bf16 bf16x8 __attribute__((ext_vector_type(8)));
typedef __bf16 bf16x4 __attribute__((ext_vector_type(4)));
typedef float f32x4 __attribute__((ext_vector_type(4)));
typedef float f32x16 __attribute__((ext_vector_type(16)));
typedef uint32_t u32x4 __attribute__((ext_vector_type(4)));

__device__ __forceinline__ f32x4 mfma16(bf16x8 a, bf16x8 b, f32x4 c) {
  return __builtin_amdgcn_mfma_f32_16x16x32_bf16(a, b, c, 0, 0, 0);
}
__device__ __forceinline__ f32x16 mfma32(bf16x8 a, bf16x8 b, f32x16 c) {
  return __builtin_amdgcn_mfma_f32_32x32x16_bf16(a, b, c, 0, 0, 0);
}

__device__ __forceinline__ float fexp2(float x) {
#if __has_builtin(__builtin_amdgcn_exp2f)
  return __builtin_amdgcn_exp2f(x);
#else
  return exp2f(x);
#endif
}

// global -> LDS direct copy, 16B per lane. LDS dst is wave-uniform base
// (HW writes base + lane*16); global src is per-lane.
__device__ __forceinline__ void gload_lds16(const void* g, void* l) {
  __builtin_amdgcn_global_load_lds(
      (__attribute__((address_space(1))) uint32_t*)(uintptr_t)g,
      (__attribute__((address_space(3))) uint32_t*)l, 16, 0, 0);
}

__device__ __forceinline__ uint32_t cvt_pk(float lo, float hi) {
  uint32_t r;
  asm volatile("v_cvt_pk_bf16_f32 %0, %1, %2" : "=v"(r) : "v"(lo), "v"(hi));
  return r;
}

// v_permlane32_swap_b32: a' = lane<32 ? a : b[lane-32]; b' = lane<32 ? a[lane+32] : b
__device__ __forceinline__ void pl_swap(uint32_t& a, uint32_t& b) {
#if __has_builtin(__builtin_amdgcn_permlane32_swap)
  typedef int i32x2_t __attribute__((ext_vector_type(2)));
  i32x2_t r = __builtin_amdgcn_permlane32_swap((int)a, (int)b, false, false);
  a = (uint32_t)r[0];
  b = (uint32_t)r[1];
#else
  uint32_t pa_ = (uint32_t)__shfl_xor((int)a, 32);
  uint32_t pb_ = (uint32_t)__shfl_xor((int)b, 32);
  bool hi_ = (threadIdx.x & 32) != 0;
  uint32_t na = hi_ ? pb_ : a;
  uint32_t nb = hi_ ? b : pa_;
  a = na;
  b = nb;
#endif
}

__device__ __forceinline__ bf16x8 pack4(uint32_t a, uint32_t b, uint32_t c,
                                        uint32_t d) {
  u32x4 v = {a, b, c, d};
  return __builtin_bit_cast(bf16x8, v);
}

// ---------------------------------------------------------------------------
// f32 -> bf16 weight conversion (4 x [1024x1024])
// ---------------------------------------------------------------------------
__global__ __launch_bounds__(256) void convert_w(
    const float* __restrict__ a, const float* __restrict__ b,
    const float* __restrict__ c, const float* __restrict__ d,
    bf16* __restrict__ out) {
  int i = (blockIdx.x * 256 + threadIdx.x) * 4;
  const float* srcs[4] = {a, b, c, d};
#pragma unroll
  for (int w = 0; w < 4; ++w) {
    f32x4 x = *(const f32x4*)(srcs[w] + i);
    bf16x4 v;
    v[0] = (bf16)x[0]; v[1] = (bf16)x[1]; v[2] = (bf16)x[2]; v[3] = (bf16)x[3];
    *(bf16x4*)(out + (size_t)w * (D_ * D_) + i) = v;
  }
}

// ---------------------------------------------------------------------------
// Fused Q/K/V projection GEMM: z = blockIdx.z selects input/weight/bias/out.
// C[8192][1024] = A @ W^T + bias. 128x128 tile, BK=64, 4 waves.
// z==0: Q, head layout, scaled by QSCALE. z==1: K, head layout.
// z==2: V, transposed head layout [B][H][HD][S].
// ---------------------------------------------------------------------------
__global__ __launch_bounds__(256, 2) void gemm_qkv(
    const float* __restrict__ Aq, const float* __restrict__ Ak,
    const float* __restrict__ Av, const bf16* __restrict__ Wb,
    const float* __restrict__ bq, const float* __restrict__ bk,
    const float* __restrict__ bv, bf16* __restrict__ Outb) {
  __shared__ alignas(128) char lds[32768];  // A: [0,16K)  B: [16K,32K)
  const int tid = threadIdx.x;
  const int lane = tid & 63;
  const int wave = tid >> 6;
  const int m0 = blockIdx.x * 128;
  const int n0 = blockIdx.y * 128;
  const int wr = wave >> 1, wc = wave & 1;
  const int z = blockIdx.z;
  const float* A = z == 0 ? Aq : (z == 1 ? Ak : Av);
  const float* bias = z == 0 ? bq : (z == 1 ? bk : bv);
  const bf16* W = Wb + (size_t)z * (D_ * D_);
  bf16* Out = Outb + (size_t)z * ((size_t)B_ * S_ * D_);
  const float oscale = (z == 0) ? QSCALE : 1.0f;

  f32x4 acc[4][4] = {};

  for (int kt = 0; kt < 16; ++kt) {
    const int k0 = kt * 64;
#pragma unroll
    for (int j = 0; j < 4; ++j) {
      int slot = j * 256 + tid;
      int row = slot >> 3, kb = slot & 7;
      const float* src = A + (size_t)(m0 + row) * D_ + k0 + (kb << 3);
      f32x4 x0 = *(const f32x4*)src;
      f32x4 x1 = *(const f32x4*)(src + 4);
      bf16x8 v;
      v[0] = (bf16)x0[0]; v[1] = (bf16)x0[1]; v[2] = (bf16)x0[2]; v[3] = (bf16)x0[3];
      v[4] = (bf16)x1[0]; v[5] = (bf16)x1[1]; v[6] = (bf16)x1[2]; v[7] = (bf16)x1[3];
      *(bf16x8*)(lds + row * 128 + ((kb ^ (row & 7)) << 4)) = v;
    }
#pragma unroll
    for (int j = 0; j < 4; ++j) {
      int slot = j * 256 + tid;
      int row = slot >> 3, kb = slot & 7;
      gload_lds16(W + (size_t)(n0 + row) * D_ + k0 + ((kb ^ (row & 7)) << 3),
                  lds + 16384 + j * 4096 + wave * 1024);
    }
    __syncthreads();
#pragma unroll
    for (int ks = 0; ks < 2; ++ks) {
      bf16x8 af[4], bfr[4];
#pragma unroll
      for (int f = 0; f < 4; ++f) {
        int ar = wr * 64 + f * 16 + (lane & 15);
        af[f] = *(const bf16x8*)(lds + ar * 128 +
                                 (((ks * 4 + (lane >> 4)) ^ (ar & 7)) << 4));
        int br = wc * 64 + f * 16 + (lane & 15);
        bfr[f] = *(const bf16x8*)(lds + 16384 + br * 128 +
                                  (((ks * 4 + (lane >> 4)) ^ (br & 7)) << 4));
      }
#pragma unroll
      for (int i = 0; i < 4; ++i)
#pragma unroll
        for (int j = 0; j < 4; ++j)
          acc[i][j] = mfma16(af[i], bfr[j], acc[i][j]);
    }
    __syncthreads();
  }

#pragma unroll
  for (int j = 0; j < 4; ++j) {
    const int col = n0 + wc * 64 + j * 16 + (lane & 15);
    const float bv_ = bias[col];
    const int h = col >> 6, hd = col & 63;
#pragma unroll
    for (int i = 0; i < 4; ++i) {
      const int row0 = m0 + wr * 64 + i * 16 + ((lane >> 4) << 2);
      if (z != 2) {  // head layout [B][H][S][HD]
#pragma unroll
        for (int r = 0; r < 4; ++r) {
          int row = row0 + r;
          int b = row >> 11, s = row & (S_ - 1);
          Out[(((size_t)(b * H_ + h) * S_ + s) << 6) + hd] =
              (bf16)((acc[i][j][r] + bv_) * oscale);
        }
      } else {  // V transposed [B][H][HD][S]; 4 acc rows are s-contiguous
        int b = row0 >> 11, s0 = row0 & (S_ - 1);
        bf16x4 pk;
#pragma unroll
        for (int r = 0; r < 4; ++r) pk[r] = (bf16)(acc[i][j][r] + bv_);
        *(bf16x4*)(Out + ((size_t)(b * H_ + h) * HD_ + hd) * S_ + s0) = pk;
      }
    }
  }
}

// ---------------------------------------------------------------------------
// Output GEMM (A bf16, f32 out): C = A @ Wo^T + bo
// ---------------------------------------------------------------------------
__global__ __launch_bounds__(256, 2) void gemm_out(
    const bf16* __restrict__ A, const bf16* __restrict__ Wb,
    const float* __restrict__ bias, float* __restrict__ Out) {
  __shared__ alignas(128) char lds[32768];
  const int tid = threadIdx.x;
  const int lane = tid & 63;
  const int wave = tid >> 6;
  const int m0 = blockIdx.x * 128;
  const int n0 = blockIdx.y * 128;
  const int wr = wave >> 1, wc = wave & 1;

  f32x4 acc[4][4] = {};

  for (int kt = 0; kt < 16; ++kt) {
    const int k0 = kt * 64;
#pragma unroll
    for (int j = 0; j < 4; ++j) {
      int slot = j * 256 + tid;
      int row = slot >> 3, kb = slot & 7;
      gload_lds16(A + (size_t)(m0 + row) * D_ + k0 + ((kb ^ (row & 7)) << 3),
                  lds + j * 4096 + wave * 1024);
    }
#pragma unroll
    for (int j = 0; j < 4; ++j) {
      int slot = j * 256 + tid;
      int row = slot >> 3, kb = slot & 7;
      gload_lds16(Wb + (size_t)(n0 + row) * D_ + k0 + ((kb ^ (row & 7)) << 3),
                  lds + 16384 + j * 4096 + wave * 1024);
    }
    __syncthreads();
#pragma unroll
    for (int ks = 0; ks < 2; ++ks) {
      bf16x8 af[4], bfr[4];
#pragma unroll
      for (int f = 0; f < 4; ++f) {
        int ar = wr * 64 + f * 16 + (lane & 15);
        af[f] = *(const bf16x8*)(lds + ar * 128 +
                                 (((ks * 4 + (lane >> 4)) ^ (ar & 7)) << 4));
        int br = wc * 64 + f * 16 + (lane & 15);
        bfr[f] = *(const bf16x8*)(lds + 16384 + br * 128 +
                                  (((ks * 4 + (lane >> 4)) ^ (br & 7)) << 4));
      }
#pragma unroll
      for (int i = 0; i < 4; ++i)
#pragma unroll
        for (int j = 0; j < 4; ++j)
          acc[i][j] = mfma16(af[i], bfr[j], acc[i][j]);
    }
    __syncthreads();
  }

#pragma unroll
  for (int j = 0; j < 4; ++j) {
    const int col = n0 + wc * 64 + j * 16 + (lane & 15);
    const float bv_ = bias[col];
#pragma unroll
    for (int i = 0; i < 4; ++i) {
      const int row0 = m0 + wr * 64 + i * 16 + ((lane >> 4) << 2);
#pragma unroll
      for (int r = 0; r < 4; ++r)
        Out[(size_t)(row0 + r) * D_ + col] = acc[i][j][r] + bv_;
    }
  }
}

// ---------------------------------------------------------------------------
// Attention v3: 32x32x16 MFMA, swapped QK^T, in-register softmax.
// Wave handles 64 q-rows (2 q-groups) -> K/V LDS frag reads shared 2x.
// Q pre-scaled by QSCALE in projection -> softmax = bare v_exp_f32.
// den accumulated via MFMA against ones-fragment (same C layout as oacc).
// Block = 4 waves x 64 q = 256 q-rows. KVBLK = 64. Double-buffered staging.
// ---------------------------------------------------------------------------
__global__ __launch_bounds__(256, 2) void attn_kernel(
    const bf16* __restrict__ Qh, const bf16* __restrict__ Kh,
    const bf16* __restrict__ Vt, bf16* __restrict__ AO) {
  // frag-major LDS: K frags 0..7 (kb*4+ks) at [0,8K); V frags 8..15
  // (kslot*2+ht) at [8K,16K); x2 double buffer.
  __shared__ alignas(128) char lds[2][16384];
  const int tid = threadIdx.x, lane = tid & 63, wave = tid >> 6;
  const int hi = lane >> 5, l31 = lane & 31;
  const int bh = blockIdx.y;
  const int q0 = blockIdx.x * 256 + wave * 64;
  const bf16* Qb = Qh + (size_t)bh * S_ * HD_;
  const bf16* Kb = Kh + (size_t)bh * S_ * HD_;
  const bf16* Vb = Vt + (size_t)bh * HD_ * S_;

  // Q B-frags (col q = l31, k = hd = ks*16 + hi*8 + j); 2 q-groups.
  bf16x8 qf[2][4];
#pragma unroll
  for (int qg = 0; qg < 2; ++qg)
#pragma unroll
    for (int ks = 0; ks < 4; ++ks)
      qf[qg][ks] = *(const bf16x8*)(Qb + (size_t)(q0 + qg * 32 + l31) * HD_ +
                                    ks * 16 + hi * 8);

  // ones B-frag for den-accumulation MFMA
  bf16x8 onesf;
#pragma unroll
  for (int j = 0; j < 8; ++j) onesf[j] = (bf16)1.0f;

  // staging: wave w stages frags {w, 4+w, 8+w, 12+w}
  const bf16* gs[4];
  int lo_[4], ginc[4];
#pragma unroll
  for (int j = 0; j < 4; ++j) {
    int f = j * 4 + wave;
    lo_[j] = f * 1024;
    if (f < 8) {  // K frag: kb = f>>2, ks = f&3
      gs[j] = Kb + (size_t)((f >> 2) * 32 + l31) * HD_ + (f & 3) * 16 + hi * 8;
      ginc[j] = 64 * HD_;
    } else {  // V frag g=f-8: ht = g&1, kslot = g>>1
      int g = f - 8;
      gs[j] = Vb + (size_t)((g & 1) * 32 + l31) * S_ + (g >> 1) * 16 + hi * 8;
      ginc[j] = 64;
    }
  }

  f32x16 oacc0[2] = {}, oacc1[2] = {};  // [ht] per q-group
  f32x16 dacc0 = {}, dacc1 = {};        // den per q-group (rows match oacc)

  // prologue: stage tile 0 into buf 0
#pragma unroll
  for (int j = 0; j < 4; ++j) {
    gload_lds16(gs[j], &lds[0][lo_[j]]);
    gs[j] += ginc[j];
  }
  __syncthreads();

  for (int t = 0; t < 32; ++t) {
    const int cur = t & 1;
    if (t < 31) {  // prefetch next tile; latency hides under compute
#pragma unroll
      for (int j = 0; j < 4; ++j) {
        gload_lds16(gs[j], &lds[cur ^ 1][lo_[j]]);
        gs[j] += ginc[j];
      }
    }
    const char* kbuf = lds[cur];
    const char* vbuf = lds[cur] + 8192;
#pragma unroll
    for (int kb = 0; kb < 2; ++kb) {
      f32x16 s0 = {}, s1 = {};
      __builtin_amdgcn_s_setprio(1);
#pragma unroll
      for (int ks = 0; ks < 4; ++ks) {
        bf16x8 kf = *(const bf16x8*)(kbuf + (kb * 4 + ks) * 1024 + lane * 16);
        s0 = mfma32(kf, qf[0][ks], s0);
        s1 = mfma32(kf, qf[1][ks], s1);
      }
      __builtin_amdgcn_s_setprio(0);
      // softmax (no max needed: logits bounded) -> bf16 A-frags
      bf16x8 pa[2][2];
#pragma unroll
      for (int qg = 0; qg < 2; ++qg) {
        f32x16 s = qg ? s1 : s0;
        f32x16 e;
#pragma unroll
        for (int r = 0; r < 16; ++r) e[r] = fexp2(s[r]);
        uint32_t w0 = cvt_pk(e[0], e[1]), w1 = cvt_pk(e[2], e[3]),
                 w2 = cvt_pk(e[4], e[5]), w3 = cvt_pk(e[6], e[7]),
                 w4 = cvt_pk(e[8], e[9]), w5 = cvt_pk(e[10], e[11]),
                 w6 = cvt_pk(e[12], e[13]), w7 = cvt_pk(e[14], e[15]);
        pl_swap(w0, w2);
        pl_swap(w1, w3);
        pl_swap(w4, w6);
        pl_swap(w5, w7);
        pa[qg][0] = pack4(w0, w1, w2, w3);  // kv 0..15 of this 32-block
        pa[qg][1] = pack4(w4, w5, w6, w7);  // kv 16..31
      }
      __builtin_amdgcn_s_setprio(1);
      // den += P @ ones  (D rows = q rows, same layout as oacc)
      dacc0 = mfma32(pa[0][0], onesf, dacc0);
      dacc0 = mfma32(pa[0][1], onesf, dacc0);
      dacc1 = mfma32(pa[1][0], onesf, dacc1);
      dacc1 = mfma32(pa[1][1], onesf, dacc1);
      // O += P @ V
#pragma unroll
      for (int ht = 0; ht < 2; ++ht) {
        bf16x8 vf0 =
            *(const bf16x8*)(vbuf + ((kb * 2 + 0) * 2 + ht) * 1024 + lane * 16);
        oacc0[ht] = mfma32(pa[0][0], vf0, oacc0[ht]);
        oacc1[ht] = mfma32(pa[1][0], vf0, oacc1[ht]);
        bf16x8 vf1 =
            *(const bf16x8*)(vbuf + ((kb * 2 + 1) * 2 + ht) * 1024 + lane * 16);
        oacc0[ht] = mfma32(pa[0][1], vf1, oacc0[ht]);
        oacc1[ht] = mfma32(pa[1][1], vf1, oacc1[ht]);
      }
      __builtin_amdgcn_s_setprio(0);
    }
    __syncthreads();  // next tile staged; cur buffer free for overwrite
  }

  // epilogue: rows of dacc match rows of oacc exactly -> no shuffles
  const int b = bh >> 4, h = bh & 15;
#pragma unroll
  for (int qg = 0; qg < 2; ++qg) {
#pragma unroll
    for (int r = 0; r < 16; ++r) {
      float rd = 1.0f / (qg ? dacc1[r] : dacc0[r]);
      int qr = (r & 3) + 8 * (r >> 2) + 4 * hi;
      size_t base = ((size_t)(b * S_ + q0 + qg * 32 + qr)) * D_ + h * 64;
      AO[base + l31] = (bf16)((qg ? oacc1[0][r] : oacc0[0][r]) * rd);
      AO[base + 32 + l31] = (bf16)((qg ? oacc1[1][r] : oacc0[1][r]) * rd);
    }
  }
}

// ---------------------------------------------------------------------------
extern "C" void kernel_launch(void* const* d_in, const int* in_sizes, int n_in,
                              void* d_out, int out_size, void* d_ws,
                              size_t ws_size, hipStream_t stream) {
  (void)in_sizes; (void)n_in; (void)out_size; (void)ws_size;
  const float* q  = (const float*)d_in[0];
  const float* k  = (const float*)d_in[1];
  const float* v  = (const float*)d_in[2];
  const float* Wq = (const float*)d_in[3];
  const float* bq = (const float*)d_in[4];
  const float* Wk = (const float*)d_in[5];
  const float* bk = (const float*)d_in[6];
  const float* Wv = (const float*)d_in[7];
  const float* bv = (const float*)d_in[8];
  const float* Wo = (const float*)d_in[9];
  const float* bo = (const float*)d_in[10];

  bf16* ws = (bf16*)d_ws;
  const size_t WSZ = (size_t)D_ * D_;
  const size_t TSZ = (size_t)B_ * S_ * D_;
  bf16* Wqkv = ws;              // Wq,Wk,Wv bf16 (z-indexed)
  bf16* Wob = ws + 3 * WSZ;
  bf16* Qh = ws + 4 * WSZ;      // z-indexed: Qh, Kh, Vt
  bf16* Kh = Qh + TSZ;
  bf16* Vt = Qh + 2 * TSZ;
  bf16* AO = Qh + 3 * TSZ;

  convert_w<<<dim3(1024), dim3(256), 0, stream>>>(Wq, Wk, Wv, Wo, ws);
  gemm_qkv<<<dim3(64, 8, 3), dim3(256), 0, stream>>>(q, k, v, Wqkv, bq, bk, bv,
                                                     Qh);
  attn_kernel<<<dim3(8, 64), dim3(256), 0, stream>>>(Qh, Kh, Vt, AO);
  gemm_out<<<dim3(64, 8), dim3(256), 0, stream>>>(AO, Wob, bo, (float*)d_out);
}